// Round 12
// baseline (319.427 us; speedup 1.0000x reference)
//
#include <hip/hip_runtime.h>
#include <hip/hip_fp16.h>
#include <math.h>

#define N_NODES 100000
#define N_EDGES 1600000
#define EP (N_EDGES + N_NODES)   // edges incl self-loops
#define HID 64
#define NCHUNK 512                               // hist/scatter chunks
#define CE (N_EDGES / NCHUNK)                    // 3125 edges per chunk (exact)
#define NBUCK 391                                // buckets of 256 node-keys
#define NTILE (N_NODES / 16)                     // 6250 MFMA tiles (exact)
#define STASH 8192                               // per-bucket stash (u32); avg fill 4092
#define OBSTRIDE 4096                            // u64 overflow slots per bucket
#define NPN 8                                    // nodes per wave (gather)

typedef _Float16 half8_t __attribute__((ext_vector_type(8)));
typedef float f32x4_t __attribute__((ext_vector_type(4)));
typedef unsigned long long u64;

// ================= bucketed CSR build v2 (order-free, u32-packed) =================

// pass 1: per-chunk LDS hist -> global totals (spread atomics)

__global__ __launch_bounds__(256)
void hist2_kernel(const int* __restrict__ dst, int* __restrict__ totals,
                  int* __restrict__ csr) {
    __shared__ int hist[NBUCK];
    const int tid = threadIdx.x, c = blockIdx.x;
    for (int b = tid; b < NBUCK; b += 256) hist[b] = 0;
    __syncthreads();
    for (int e = c * CE + tid; e < (c + 1) * CE; e += 256)
        atomicAdd(&hist[dst[e] >> 8], 1);
    __syncthreads();
    for (int b = tid; b < NBUCK; b += 256)
        if (hist[b]) atomicAdd(&totals[b], hist[b]);
    if (c == 0 && tid < 64) csr[EP + tid] = 0;   // zero pad for gather over-read
}

// pass 2: one block scans 391 totals -> bbase (exclusive), init gcur

__global__ __launch_bounds__(512)
void bucket_base_kernel(const int* __restrict__ totals, int* __restrict__ bbase,
                        int* __restrict__ gcur) {
    __shared__ int tmp[512];
    const int t = threadIdx.x;
    int v = (t < NBUCK) ? totals[t] : 0;
    tmp[t] = v;
    __syncthreads();
    for (int off = 1; off < 512; off <<= 1) {
        int y = (t >= off) ? tmp[t - off] : 0;
        __syncthreads();
        tmp[t] += y;
        __syncthreads();
    }
    int excl = tmp[t] - v;
    if (t <= NBUCK) bbase[t] = excl;     // bbase[NBUCK] = N_EDGES
    if (t < NBUCK) gcur[t] = excl;
}

// pass 3: per-chunk count -> atomic range reservation -> u32-packed scatter

__global__ __launch_bounds__(256)
void scatter2_kernel(const int* __restrict__ src, const int* __restrict__ dst,
                     int* __restrict__ gcur, unsigned* __restrict__ ebuf) {
    __shared__ int hist[NBUCK];
    __shared__ int cur[NBUCK];
    const int tid = threadIdx.x, c = blockIdx.x;
    for (int b = tid; b < NBUCK; b += 256) hist[b] = 0;
    __syncthreads();
    for (int e = c * CE + tid; e < (c + 1) * CE; e += 256)
        atomicAdd(&hist[dst[e] >> 8], 1);
    __syncthreads();
    for (int b = tid; b < NBUCK; b += 256)
        cur[b] = hist[b] ? atomicAdd(&gcur[b], hist[b]) : 0;
    __syncthreads();
    for (int e = c * CE + tid; e < (c + 1) * CE; e += 256) {
        int d = dst[e], s = src[e];
        int p = atomicAdd(&cur[d >> 8], 1);
        ebuf[p] = ((unsigned)(d & 255) << 17) | (unsigned)s;   // src < 2^17
    }
}

// pass 4: per-bucket rank via LDS atomic-return; cnt scan -> rowptr/dinv/self-loop; csr fill

__global__ __launch_bounds__(256)
void rankfill_kernel(const unsigned* __restrict__ ebuf, const int* __restrict__ bbase,
                     u64* __restrict__ obuf, int* __restrict__ rowptr,
                     int* __restrict__ csr, float* __restrict__ dinv) {
    __shared__ int cnt[256];
    __shared__ int rpl[256];
    __shared__ int wsum[4];
    __shared__ int ocnt;
    __shared__ unsigned stash[STASH];
    const int tid = threadIdx.x, b = blockIdx.x;
    cnt[tid] = 0;
    if (tid == 0) ocnt = 0;
    __syncthreads();
    const int R0 = bbase[b], R1 = bbase[b + 1];
    const int RL = R1 - R0;
    for (int off = tid; off < RL; off += 256) {
        unsigned v = ebuf[R0 + off];
        int key = (v >> 17) & 0xFF;
        int r = atomicAdd(&cnt[key], 1);
        if (off < STASH && r < 128) {
            stash[off] = ((unsigned)r << 25) | v;      // max valid 0xFFF1869F < sentinel
        } else {
            if (off < STASH) stash[off] = 0xFFFFFFFFu;
            int oi = (off >= STASH) ? (off - STASH) : (2048 + atomicAdd(&ocnt, 1));
            obuf[(size_t)b * OBSTRIDE + oi] =
                ((u64)r << 40) | ((u64)key << 32) | (u64)(v & 0x1FFFFu);
        }
    }
    __syncthreads();
    // exclusive block scan of cnt[256]
    const int lane = tid & 63, w = tid >> 6;
    int x = cnt[tid];
    int inc = x;
#pragma unroll
    for (int off = 1; off < 64; off <<= 1) {
        int y = __shfl_up(inc, off, 64);
        if (lane >= off) inc += y;
    }
    if (lane == 63) wsum[w] = inc;
    __syncthreads();
    int base = 0;
    for (int k = 0; k < 4; ++k) if (k < w) base += wsum[k];
    int pre = base + inc - x;
    const int n = b * 256 + tid;
    const int rpn = R0 + n + pre;     // edges before + one self-loop per preceding node
    rpl[tid] = rpn;
    if (n < N_NODES) {
        rowptr[n] = rpn;
        dinv[n] = rsqrtf((float)(x + 1));
        csr[rpn + x] = n;             // self-loop at end of node's list
    }
    if (b == NBUCK - 1 && tid == 0) rowptr[N_NODES] = EP;
    __syncthreads();
    const int lim = (RL < STASH) ? RL : STASH;
    for (int off = tid; off < lim; off += 256) {
        unsigned v = stash[off];
        if (v == 0xFFFFFFFFu) continue;
        csr[rpl[(v >> 17) & 0xFF] + (v >> 25)] = (int)(v & 0x1FFFFu);
    }
    for (int j = tid; j < RL - STASH; j += 256) {       // ≈ never
        u64 pk = obuf[(size_t)b * OBSTRIDE + j];
        csr[rpl[(pk >> 32) & 0xFF] + (int)(pk >> 40)] = (int)(pk & 0x1FFFFu);
    }
    for (int j = tid; j < ocnt; j += 256) {             // ≈ never
        u64 pk = obuf[(size_t)b * OBSTRIDE + 2048 + j];
        csr[rpl[(pk >> 32) & 0xFF] + (int)(pk >> 40)] = (int)(pk & 0x1FFFFu);
    }
}

// ---------------- layer 1: gf = fp16( dinv * (x @ W1) ), [N][64] ----------------

__global__ void layer1_kernel(const float* __restrict__ x, const float* __restrict__ W1,
                              const float* __restrict__ dinv, __half* __restrict__ gf) {
    int idx = blockIdx.x * blockDim.x + threadIdx.x;
    if (idx >= N_NODES * HID) return;
    int n = idx >> 6, c = idx & 63;
    float v = x[n * 3 + 0] * W1[c] + x[n * 3 + 1] * W1[HID + c]
            + x[n * 3 + 2] * W1[2 * HID + c];
    gf[idx] = __float2half(v * dinv[n]);
}

// ---------------- gather v2: shfl-free address chain ----------------
// Group g (16 lanes) loads its edge index via a wave-uniform csr load (HW
// broadcast, L1-hot) then the 128B feature row slice. All csr/feature loads
// are independent across k-rounds and nodes -> deep pipelining. Adds are
// predicated; loads are unconditional (csr padded, values are valid node ids).

__device__ __forceinline__ void addp(float4& a, uint2 u, bool pred) {
    __half2 h0 = *(__half2*)&u.x, h1 = *(__half2*)&u.y;
    float2 x = __half22float2(h0), y = __half22float2(h1);
    if (pred) { a.x += x.x; a.y += x.y; a.z += y.x; a.w += y.y; }
}

__global__ __launch_bounds__(256)
void gather_kernel(const __half* __restrict__ gf, const int* __restrict__ rowptr,
                   const int* __restrict__ csr, float* __restrict__ agg) {
    const int lane = threadIdx.x & 63, wid = threadIdx.x >> 6;
    const int g = lane >> 4, p = lane & 15;
    const int n0 = (blockIdx.x * 4 + wid) * NPN;
    const uint2* gf2 = (const uint2*)gf;
#pragma unroll
    for (int i = 0; i < NPN; ++i) {
        const int n = n0 + i;
        const int beg = rowptr[n], end = rowptr[n + 1];
        const int cnt = end - beg;
        float4 acc0 = make_float4(0.f, 0.f, 0.f, 0.f);
        float4 acc1 = make_float4(0.f, 0.f, 0.f, 0.f);
        int s0 = csr[beg + g];
        int s1 = csr[beg + g + 4];
        int s2 = csr[beg + g + 8];
        int s3 = csr[beg + g + 12];
        uint2 u0 = gf2[(size_t)s0 * 16 + p];
        uint2 u1 = gf2[(size_t)s1 * 16 + p];
        uint2 u2 = gf2[(size_t)s2 * 16 + p];
        uint2 u3 = gf2[(size_t)s3 * 16 + p];
        addp(acc0, u0, g + 0 < cnt);
        addp(acc1, u1, g + 4 < cnt);
        addp(acc0, u2, g + 8 < cnt);
        addp(acc1, u3, g + 12 < cnt);
        if (cnt > 16) {
            s0 = csr[beg + g + 16];
            s1 = csr[beg + g + 20];
            s2 = csr[beg + g + 24];
            s3 = csr[beg + g + 28];
            u0 = gf2[(size_t)s0 * 16 + p];
            u1 = gf2[(size_t)s1 * 16 + p];
            u2 = gf2[(size_t)s2 * 16 + p];
            u3 = gf2[(size_t)s3 * 16 + p];
            addp(acc0, u0, g + 16 < cnt);
            addp(acc1, u1, g + 20 < cnt);
            addp(acc0, u2, g + 24 < cnt);
            addp(acc1, u3, g + 28 < cnt);
            if (cnt > 32) {              // rare tail
                for (int e = 32 + g; e < cnt; e += 4) {
                    int s = csr[beg + e];
                    uint2 u = gf2[(size_t)s * 16 + p];
                    addp(acc0, u, true);
                }
            }
        }
        float4 acc = make_float4(acc0.x + acc1.x, acc0.y + acc1.y,
                                 acc0.z + acc1.z, acc0.w + acc1.w);
        acc.x += __shfl_xor(acc.x, 16, 64);
        acc.y += __shfl_xor(acc.y, 16, 64);
        acc.z += __shfl_xor(acc.z, 16, 64);
        acc.w += __shfl_xor(acc.w, 16, 64);
        acc.x += __shfl_xor(acc.x, 32, 64);
        acc.y += __shfl_xor(acc.y, 32, 64);
        acc.z += __shfl_xor(acc.z, 32, 64);
        acc.w += __shfl_xor(acc.w, 32, 64);
        if (g == 0) ((float4*)(agg + (size_t)n * HID))[p] = acc;
    }
}

// ================= MFMA transform: hv = relu(di*agg+b); gf_out = fp16(di*(hv@W)) =================

__device__ __forceinline__ void hv_to_tile(const float* __restrict__ agg,
                                           const float* __restrict__ dinv,
                                           const float* __restrict__ bprev,
                                           int n0, int lane, _Float16* __restrict__ tl) {
    const int r = lane >> 2, cg = lane & 3;
    const float dr = dinv[n0 + r];
    const float4* arow = (const float4*)(agg + (size_t)(n0 + r) * HID + cg * 16);
    const float4* brow = (const float4*)(bprev + cg * 16);
    float4 a0 = arow[0], a1 = arow[1], a2 = arow[2], a3 = arow[3];
    float4 b0 = brow[0], b1 = brow[1], b2 = brow[2], b3 = brow[3];
    half8_t h0, h1;
    h0[0] = (_Float16)fmaxf(fmaf(dr, a0.x, b0.x), 0.f);
    h0[1] = (_Float16)fmaxf(fmaf(dr, a0.y, b0.y), 0.f);
    h0[2] = (_Float16)fmaxf(fmaf(dr, a0.z, b0.z), 0.f);
    h0[3] = (_Float16)fmaxf(fmaf(dr, a0.w, b0.w), 0.f);
    h0[4] = (_Float16)fmaxf(fmaf(dr, a1.x, b1.x), 0.f);
    h0[5] = (_Float16)fmaxf(fmaf(dr, a1.y, b1.y), 0.f);
    h0[6] = (_Float16)fmaxf(fmaf(dr, a1.z, b1.z), 0.f);
    h0[7] = (_Float16)fmaxf(fmaf(dr, a1.w, b1.w), 0.f);
    h1[0] = (_Float16)fmaxf(fmaf(dr, a2.x, b2.x), 0.f);
    h1[1] = (_Float16)fmaxf(fmaf(dr, a2.y, b2.y), 0.f);
    h1[2] = (_Float16)fmaxf(fmaf(dr, a2.z, b2.z), 0.f);
    h1[3] = (_Float16)fmaxf(fmaf(dr, a2.w, b2.w), 0.f);
    h1[4] = (_Float16)fmaxf(fmaf(dr, a3.x, b3.x), 0.f);
    h1[5] = (_Float16)fmaxf(fmaf(dr, a3.y, b3.y), 0.f);
    h1[6] = (_Float16)fmaxf(fmaf(dr, a3.z, b3.z), 0.f);
    h1[7] = (_Float16)fmaxf(fmaf(dr, a3.w, b3.w), 0.f);
    *(half8_t*)(tl + r * 72 + cg * 16) = h0;
    *(half8_t*)(tl + r * 72 + cg * 16 + 8) = h1;
}

__global__ __launch_bounds__(256, 3)
void mfma_transform_kernel(const float* __restrict__ agg, const float* __restrict__ dinv,
                           const float* __restrict__ bprev, const float* __restrict__ W,
                           __half* __restrict__ gf_out) {
    __shared__ __align__(16) _Float16 tile[4][16 * 72];
    const int lane = threadIdx.x & 63, wid = threadIdx.x >> 6;
    const int tid4 = blockIdx.x * 4 + wid;
    if (tid4 >= NTILE) return;
    const int n0 = tid4 * 16;
    _Float16* tl = &tile[wid][0];

    hv_to_tile(agg, dinv, bprev, n0, lane, tl);

    const int kg = lane >> 4, n = lane & 15;
    half8_t B[4][2];
#pragma unroll
    for (int t = 0; t < 4; ++t)
#pragma unroll
        for (int h = 0; h < 2; ++h)
#pragma unroll
            for (int j = 0; j < 8; ++j)
                B[t][h][j] = (_Float16)W[(h * 32 + kg * 8 + j) * HID + t * 16 + n];

    __builtin_amdgcn_s_waitcnt(0);   // drain lgkm before cross-lane LDS read
    half8_t A0 = *(const half8_t*)(tl + n * 72 + kg * 8);
    half8_t A1 = *(const half8_t*)(tl + n * 72 + 32 + kg * 8);

    f32x4_t C[4];
#pragma unroll
    for (int t = 0; t < 4; ++t) {
        f32x4_t c = {0.f, 0.f, 0.f, 0.f};
        c = __builtin_amdgcn_mfma_f32_16x16x32_f16(A0, B[t][0], c, 0, 0, 0);
        c = __builtin_amdgcn_mfma_f32_16x16x32_f16(A1, B[t][1], c, 0, 0, 0);
        C[t] = c;
    }

    const int q = lane >> 4;
    float di4[4];
#pragma unroll
    for (int r = 0; r < 4; ++r) di4[r] = dinv[n0 + q * 4 + r];
#pragma unroll
    for (int t = 0; t < 4; ++t)
#pragma unroll
        for (int r = 0; r < 4; ++r)
            tl[(q * 4 + r) * 72 + t * 16 + n] = (_Float16)(C[t][r] * di4[r]);
    __builtin_amdgcn_s_waitcnt(0);
    const int r2 = lane >> 2, ch = lane & 3;
    uint4 v0 = *(const uint4*)(tl + r2 * 72 + ch * 16);
    uint4 v1 = *(const uint4*)(tl + r2 * 72 + ch * 16 + 8);
    *(uint4*)((__half*)gf_out + (size_t)(n0 + r2) * HID + ch * 16) = v0;
    *(uint4*)((__half*)gf_out + (size_t)(n0 + r2) * HID + ch * 16 + 8) = v1;
}

// ================= MFMA final: hv + MFMA (Wm1) + head + sigmoid =================

__global__ __launch_bounds__(256, 3)
void mfma_final_kernel(const float* __restrict__ agg, const float* __restrict__ dinv,
                       const float* __restrict__ b3, const float* __restrict__ Wm1,
                       const float* __restrict__ bm1, const float* __restrict__ Wm2,
                       const float* __restrict__ bm2, float* __restrict__ out) {
    __shared__ __align__(16) _Float16 tile[4][16 * 72];
    const int lane = threadIdx.x & 63, wid = threadIdx.x >> 6;
    const int tid4 = blockIdx.x * 4 + wid;
    if (tid4 >= NTILE) return;
    const int n0 = tid4 * 16;
    _Float16* tl = &tile[wid][0];

    hv_to_tile(agg, dinv, b3, n0, lane, tl);

    const int kg = lane >> 4, n = lane & 15;
    half8_t B[4][2];
#pragma unroll
    for (int t = 0; t < 4; ++t)
#pragma unroll
        for (int h = 0; h < 2; ++h)
#pragma unroll
            for (int j = 0; j < 8; ++j)
                B[t][h][j] = (_Float16)Wm1[(h * 32 + kg * 8 + j) * HID + t * 16 + n];

    __builtin_amdgcn_s_waitcnt(0);
    half8_t A0 = *(const half8_t*)(tl + n * 72 + kg * 8);
    half8_t A1 = *(const half8_t*)(tl + n * 72 + 32 + kg * 8);

    f32x4_t C[4];
#pragma unroll
    for (int t = 0; t < 4; ++t) {
        f32x4_t c = {0.f, 0.f, 0.f, 0.f};
        c = __builtin_amdgcn_mfma_f32_16x16x32_f16(A0, B[t][0], c, 0, 0, 0);
        c = __builtin_amdgcn_mfma_f32_16x16x32_f16(A1, B[t][1], c, 0, 0, 0);
        C[t] = c;
    }

    float bm14[4], wm24[4];
#pragma unroll
    for (int t = 0; t < 4; ++t) { bm14[t] = bm1[t * 16 + n]; wm24[t] = Wm2[t * 16 + n]; }
    const float bm20 = bm2[0];
    float part[4] = {0.f, 0.f, 0.f, 0.f};
#pragma unroll
    for (int t = 0; t < 4; ++t)
#pragma unroll
        for (int r = 0; r < 4; ++r)
            part[r] += fmaxf(C[t][r] + bm14[t], 0.0f) * wm24[t];
#pragma unroll
    for (int off = 1; off < 16; off <<= 1)
#pragma unroll
        for (int r = 0; r < 4; ++r) part[r] += __shfl_xor(part[r], off, 64);
    if (n == 0) {
        const int q = lane >> 4;
#pragma unroll
        for (int r = 0; r < 4; ++r)
            out[n0 + q * 4 + r] = 1.0f / (1.0f + expf(-(part[r] + bm20)));
    }
}

// ---------------- launch ----------------

extern "C" void kernel_launch(void* const* d_in, const int* in_sizes, int n_in,
                              void* d_out, int out_size, void* d_ws, size_t ws_size,
                              hipStream_t stream) {
    const float* x   = (const float*)d_in[0];
    const int*   ei  = (const int*)d_in[1];
    const float* W1  = (const float*)d_in[2];
    const float* b1  = (const float*)d_in[3];
    const float* W2  = (const float*)d_in[4];
    const float* b2  = (const float*)d_in[5];
    const float* W3  = (const float*)d_in[6];
    const float* b3  = (const float*)d_in[7];
    const float* Wm1 = (const float*)d_in[8];
    const float* bm1 = (const float*)d_in[9];
    const float* Wm2 = (const float*)d_in[10];
    const float* bm2 = (const float*)d_in[11];
    float* out = (float*)d_out;

    const int* src = ei;
    const int* dst = ei + N_EDGES;

    char* ws = (char*)d_ws;
    size_t off = 0;
    auto alloc = [&](size_t bytes) { size_t o = off; off = (off + bytes + 255) & ~(size_t)255; return (void*)(ws + o); };
    int*    rowptr = (int*)alloc(4ll * (N_NODES + 1));
    int*    totals = (int*)alloc(4ll * NBUCK);
    int*    bbase  = (int*)alloc(4ll * (NBUCK + 1));
    int*    gcur   = (int*)alloc(4ll * NBUCK);
    int*    csr    = (int*)alloc(4ll * (EP + 64));       // +64 pad (zeros)
    float*  dinv   = (float*)alloc(4ll * N_NODES);
    __half* gfA    = (__half*)alloc(2ll * N_NODES * HID);
    __half* gfB    = (__half*)alloc(2ll * N_NODES * HID);
    float*  agg    = (float*)alloc(4ll * N_NODES * HID); // fp32 [N][64], 25.6 MB
    // preamble-only, alias agg: ebuf 6.4 MB + obuf 12.8 MB = 19.2 <= 25.6
    unsigned* ebuf = (unsigned*)agg;
    u64*      obuf = (u64*)((char*)agg + 4ll * N_EDGES);
    (void)ws_size;

    // --- CSR build v2: 4 kernels + 1 tiny memset ---
    hipMemsetAsync(totals, 0, 4ll * NBUCK, stream);
    hist2_kernel<<<NCHUNK, 256, 0, stream>>>(dst, totals, csr);
    bucket_base_kernel<<<1, 512, 0, stream>>>(totals, bbase, gcur);
    scatter2_kernel<<<NCHUNK, 256, 0, stream>>>(src, dst, gcur, ebuf);
    rankfill_kernel<<<NBUCK, 256, 0, stream>>>(ebuf, bbase, obuf, rowptr, csr, dinv);

    // --- layers (split gather + MFMA transform) ---
    const int gblocks = N_NODES / (4 * NPN);   // 3125, exact
    const int fblocks = (NTILE + 3) / 4;       // 1563
    layer1_kernel<<<(N_NODES * HID + 255) / 256, 256, 0, stream>>>(x, W1, dinv, gfA);
    gather_kernel<<<gblocks, 256, 0, stream>>>(gfA, rowptr, csr, agg);
    mfma_transform_kernel<<<fblocks, 256, 0, stream>>>(agg, dinv, b1, W2, gfB);
    gather_kernel<<<gblocks, 256, 0, stream>>>(gfB, rowptr, csr, agg);
    mfma_transform_kernel<<<fblocks, 256, 0, stream>>>(agg, dinv, b2, W3, gfA);
    gather_kernel<<<gblocks, 256, 0, stream>>>(gfA, rowptr, csr, agg);
    mfma_final_kernel<<<fblocks, 256, 0, stream>>>(agg, dinv, b3, Wm1, bm1, Wm2, bm2, out);
}

// Round 13
// 288.511 us; speedup vs baseline: 1.1072x; 1.1072x over previous
//
#include <hip/hip_runtime.h>
#include <hip/hip_fp16.h>
#include <math.h>

#define N_NODES 100000
#define N_EDGES 1600000
#define EP (N_EDGES + N_NODES)   // edges incl self-loops
#define HID 64
#define NCHUNK 512                               // hist/scatter chunks
#define CE (N_EDGES / NCHUNK)                    // 3125 edges per chunk (exact)
#define NBUCK 391                                // buckets of 256 node-keys
#define NHIST (NBUCK * NCHUNK)                   // 200192
#define NHB ((NHIST + 1023) / 1024)              // 196 scan blocks
#define NTILE (N_NODES / 16)                     // 6250 MFMA tiles (exact)
#define STASH 8192                               // per-bucket stash (u32)
#define OBSTRIDE 4096                            // u64 overflow slots per bucket
#define NPN 4                                    // nodes per wave (gather)

typedef _Float16 half8_t __attribute__((ext_vector_type(8)));
typedef float f32x4_t __attribute__((ext_vector_type(4)));
typedef unsigned long long u64;

// ================= bucketed CSR build v3 (5 dispatches, no memset) =================

// pass 1: per-chunk LDS hist -> histA[b*NCHUNK+c] (plain stores; all slots written)

__global__ __launch_bounds__(256)
void hist_kernel(const int* __restrict__ dst, int* __restrict__ histA,
                 int* __restrict__ csr) {
    __shared__ int hist[NBUCK];
    const int tid = threadIdx.x, c = blockIdx.x;
    for (int b = tid; b < NBUCK; b += 256) hist[b] = 0;
    __syncthreads();
    for (int e = c * CE + tid; e < (c + 1) * CE; e += 256)
        atomicAdd(&hist[dst[e] >> 8], 1);
    __syncthreads();
    for (int b = tid; b < NBUCK; b += 256) histA[b * NCHUNK + c] = hist[b];
    if (c == 0 && tid < 64) csr[EP + tid] = 0;   // zero pad for gather over-read
}

// pass 2a: per-block EXCLUSIVE scan of histA -> baseL; block totals -> bsum

__global__ void scang_block(const int* __restrict__ in, int* __restrict__ baseL,
                            int* __restrict__ bsum) {
    __shared__ int wsum[16];
    int tid = threadIdx.x, lane = tid & 63, wid = tid >> 6;
    int i = blockIdx.x * 1024 + tid;
    int x = (i < NHIST) ? in[i] : 0;
    int inc = x;
#pragma unroll
    for (int off = 1; off < 64; off <<= 1) {
        int y = __shfl_up(inc, off, 64);
        if (lane >= off) inc += y;
    }
    if (lane == 63) wsum[wid] = inc;
    __syncthreads();
    if (tid == 0) {
        int s = 0;
#pragma unroll
        for (int j = 0; j < 16; ++j) { int t2 = wsum[j]; wsum[j] = s; s += t2; }
    }
    __syncthreads();
    if (i < NHIST) baseL[i] = wsum[wid] + inc - x;   // local exclusive
    if (tid == 1023) bsum[blockIdx.x] = wsum[15] + inc;   // block total
}

// pass 2b: exclusive scan of 196 block totals

__global__ void scang_bsum(int* __restrict__ bsum) {
    __shared__ int tmp[256];
    int t = threadIdx.x;
    tmp[t] = (t < NHB) ? bsum[t] : 0;
    __syncthreads();
    for (int off = 1; off < 256; off <<= 1) {
        int v = (t >= off) ? tmp[t - off] : 0;
        __syncthreads();
        tmp[t] += v;
        __syncthreads();
    }
    if (t < NHB) bsum[t] = (t == 0) ? 0 : tmp[t - 1];
}

// pass 3: scatter u32-packed (key,src); base = baseL + bsum-offset (on the fly)

__global__ __launch_bounds__(256)
void scatter_kernel(const int* __restrict__ src, const int* __restrict__ dst,
                    const int* __restrict__ baseL, const int* __restrict__ bsum,
                    unsigned* __restrict__ ebuf) {
    __shared__ int cur[NBUCK];
    const int tid = threadIdx.x, c = blockIdx.x;
    for (int b = tid; b < NBUCK; b += 256) {
        int idx = b * NCHUNK + c;
        cur[b] = baseL[idx] + bsum[idx >> 10];
    }
    __syncthreads();
    for (int e = c * CE + tid; e < (c + 1) * CE; e += 256) {
        int d = dst[e], s = src[e];
        int p = atomicAdd(&cur[d >> 8], 1);
        ebuf[p] = ((unsigned)(d & 255) << 17) | (unsigned)s;   // src < 2^17
    }
}

// pass 4: per-bucket rank; cnt scan -> rowptr/dinv/self-loop; csr fill

__global__ __launch_bounds__(256)
void rankfill_kernel(const unsigned* __restrict__ ebuf, const int* __restrict__ baseL,
                     const int* __restrict__ bsum, u64* __restrict__ obuf,
                     int* __restrict__ rowptr, int* __restrict__ csr,
                     float* __restrict__ dinv) {
    __shared__ int cnt[256];
    __shared__ int rpl[256];
    __shared__ int wsum[4];
    __shared__ int ocnt;
    __shared__ unsigned stash[STASH];
    const int tid = threadIdx.x, b = blockIdx.x;
    cnt[tid] = 0;
    if (tid == 0) ocnt = 0;
    __syncthreads();
    const int i0 = b * NCHUNK;
    const int R0 = baseL[i0] + bsum[i0 >> 10];
    const int i1 = (b + 1) * NCHUNK;
    const int R1 = (b == NBUCK - 1) ? N_EDGES : (baseL[i1] + bsum[i1 >> 10]);
    const int RL = R1 - R0;
    for (int off = tid; off < RL; off += 256) {
        unsigned v = ebuf[R0 + off];
        int key = (v >> 17) & 0xFF;
        int r = atomicAdd(&cnt[key], 1);
        if (off < STASH && r < 128) {
            stash[off] = ((unsigned)r << 25) | v;      // max valid < 0xFFFFFFFF
        } else {
            if (off < STASH) stash[off] = 0xFFFFFFFFu;
            int oi = (off >= STASH) ? (off - STASH) : (2048 + atomicAdd(&ocnt, 1));
            obuf[(size_t)b * OBSTRIDE + oi] =
                ((u64)r << 40) | ((u64)key << 32) | (u64)(v & 0x1FFFFu);
        }
    }
    __syncthreads();
    const int lane = tid & 63, w = tid >> 6;
    int x = cnt[tid];
    int inc = x;
#pragma unroll
    for (int off = 1; off < 64; off <<= 1) {
        int y = __shfl_up(inc, off, 64);
        if (lane >= off) inc += y;
    }
    if (lane == 63) wsum[w] = inc;
    __syncthreads();
    int base = 0;
    for (int k = 0; k < 4; ++k) if (k < w) base += wsum[k];
    int pre = base + inc - x;
    const int n = b * 256 + tid;
    const int rpn = R0 + n + pre;     // edges before + one self-loop per preceding node
    rpl[tid] = rpn;
    if (n < N_NODES) {
        rowptr[n] = rpn;
        dinv[n] = rsqrtf((float)(x + 1));
        csr[rpn + x] = n;             // self-loop at end of node's list
    }
    if (b == NBUCK - 1 && tid == 0) rowptr[N_NODES] = EP;
    __syncthreads();
    const int lim = (RL < STASH) ? RL : STASH;
    for (int off = tid; off < lim; off += 256) {
        unsigned v = stash[off];
        if (v == 0xFFFFFFFFu) continue;
        csr[rpl[(v >> 17) & 0xFF] + (v >> 25)] = (int)(v & 0x1FFFFu);
    }
    for (int j = tid; j < RL - STASH; j += 256) {       // ≈ never
        u64 pk = obuf[(size_t)b * OBSTRIDE + j];
        csr[rpl[(pk >> 32) & 0xFF] + (int)(pk >> 40)] = (int)(pk & 0x1FFFFu);
    }
    for (int j = tid; j < ocnt; j += 256) {             // ≈ never
        u64 pk = obuf[(size_t)b * OBSTRIDE + 2048 + j];
        csr[rpl[(pk >> 32) & 0xFF] + (int)(pk >> 40)] = (int)(pk & 0x1FFFFu);
    }
}

// ---------------- layer 1: gf = fp16( dinv * (x @ W1) ), [N][64] ----------------

__global__ void layer1_kernel(const float* __restrict__ x, const float* __restrict__ W1,
                              const float* __restrict__ dinv, __half* __restrict__ gf) {
    int idx = blockIdx.x * blockDim.x + threadIdx.x;
    if (idx >= N_NODES * HID) return;
    int n = idx >> 6, c = idx & 63;
    float v = x[n * 3 + 0] * W1[c] + x[n * 3 + 1] * W1[HID + c]
            + x[n * 3 + 2] * W1[2 * HID + c];
    gf[idx] = __float2half(v * dinv[n]);
}

// ---------------- gather (R8/R11-proven inner loop; NPN=4 for occupancy) ----------------

__global__ __launch_bounds__(256)
void gather_kernel(const __half* __restrict__ gf, const int* __restrict__ rowptr,
                   const int* __restrict__ csr, float* __restrict__ agg) {
    const int lane = threadIdx.x & 63, wid = threadIdx.x >> 6;
    const int g = lane >> 4, p = lane & 15;
    const int n0 = (blockIdx.x * 4 + wid) * NPN;
    int rp = rowptr[n0 + min(lane, NPN)];   // NPN+1 lanes valid
    const uint2* gf2 = (const uint2*)gf;    // node s slice p -> gf2[s*16+p]
    int begv[NPN], cntv[NPN], idxv[NPN];
    int end_prev = __shfl(rp, 0, 64);
#pragma unroll
    for (int i = 0; i < NPN; ++i) {         // independent index loads in flight
        int end = __shfl(rp, i + 1, 64);
        begv[i] = end_prev;
        cntv[i] = end - end_prev;
        end_prev = end;
        idxv[i] = csr[begv[i] + lane];      // safe: csr padded by 64
    }
#pragma unroll
    for (int i = 0; i < NPN; ++i) {
        const int n = n0 + i;
        const int cnt = cntv[i], beg = begv[i], iv = idxv[i];
        float4 acc = make_float4(0.f, 0.f, 0.f, 0.f);
#pragma unroll
        for (int k = 0; k < 4; ++k) {
            int e = g + 4 * k;
            int s = __shfl(iv, e, 64);
            uint2 u = gf2[(size_t)s * 16 + p];
            __half2 h0 = *(__half2*)&u.x, h1 = *(__half2*)&u.y;
            float2 a = __half22float2(h0), b = __half22float2(h1);
            if (e < cnt) { acc.x += a.x; acc.y += a.y; acc.z += b.x; acc.w += b.y; }
        }
        if (cnt > 16) {
#pragma unroll
            for (int k = 4; k < 8; ++k) {
                int e = g + 4 * k;
                int s = __shfl(iv, e, 64);
                uint2 u = gf2[(size_t)s * 16 + p];
                __half2 h0 = *(__half2*)&u.x, h1 = *(__half2*)&u.y;
                float2 a = __half22float2(h0), b = __half22float2(h1);
                if (e < cnt) { acc.x += a.x; acc.y += a.y; acc.z += b.x; acc.w += b.y; }
            }
            if (cnt > 32) {          // rare tail
                for (int e = 32 + g; e < cnt; e += 4) {
                    int s = (e < 64) ? __shfl(iv, e, 64) : csr[beg + e];
                    uint2 u = gf2[(size_t)s * 16 + p];
                    __half2 h0 = *(__half2*)&u.x, h1 = *(__half2*)&u.y;
                    float2 a = __half22float2(h0), b = __half22float2(h1);
                    acc.x += a.x; acc.y += a.y; acc.z += b.x; acc.w += b.y;
                }
            }
        }
        acc.x += __shfl_xor(acc.x, 16, 64);
        acc.y += __shfl_xor(acc.y, 16, 64);
        acc.z += __shfl_xor(acc.z, 16, 64);
        acc.w += __shfl_xor(acc.w, 16, 64);
        acc.x += __shfl_xor(acc.x, 32, 64);
        acc.y += __shfl_xor(acc.y, 32, 64);
        acc.z += __shfl_xor(acc.z, 32, 64);
        acc.w += __shfl_xor(acc.w, 32, 64);
        if (g == 0) ((float4*)(agg + (size_t)n * HID))[p] = acc;
    }
}

// ================= MFMA transform: hv = relu(di*agg+b); gf_out = fp16(di*(hv@W)) =================

__device__ __forceinline__ void hv_to_tile(const float* __restrict__ agg,
                                           const float* __restrict__ dinv,
                                           const float* __restrict__ bprev,
                                           int n0, int lane, _Float16* __restrict__ tl) {
    const int r = lane >> 2, cg = lane & 3;
    const float dr = dinv[n0 + r];
    const float4* arow = (const float4*)(agg + (size_t)(n0 + r) * HID + cg * 16);
    const float4* brow = (const float4*)(bprev + cg * 16);
    float4 a0 = arow[0], a1 = arow[1], a2 = arow[2], a3 = arow[3];
    float4 b0 = brow[0], b1 = brow[1], b2 = brow[2], b3 = brow[3];
    half8_t h0, h1;
    h0[0] = (_Float16)fmaxf(fmaf(dr, a0.x, b0.x), 0.f);
    h0[1] = (_Float16)fmaxf(fmaf(dr, a0.y, b0.y), 0.f);
    h0[2] = (_Float16)fmaxf(fmaf(dr, a0.z, b0.z), 0.f);
    h0[3] = (_Float16)fmaxf(fmaf(dr, a0.w, b0.w), 0.f);
    h0[4] = (_Float16)fmaxf(fmaf(dr, a1.x, b1.x), 0.f);
    h0[5] = (_Float16)fmaxf(fmaf(dr, a1.y, b1.y), 0.f);
    h0[6] = (_Float16)fmaxf(fmaf(dr, a1.z, b1.z), 0.f);
    h0[7] = (_Float16)fmaxf(fmaf(dr, a1.w, b1.w), 0.f);
    h1[0] = (_Float16)fmaxf(fmaf(dr, a2.x, b2.x), 0.f);
    h1[1] = (_Float16)fmaxf(fmaf(dr, a2.y, b2.y), 0.f);
    h1[2] = (_Float16)fmaxf(fmaf(dr, a2.z, b2.z), 0.f);
    h1[3] = (_Float16)fmaxf(fmaf(dr, a2.w, b2.w), 0.f);
    h1[4] = (_Float16)fmaxf(fmaf(dr, a3.x, b3.x), 0.f);
    h1[5] = (_Float16)fmaxf(fmaf(dr, a3.y, b3.y), 0.f);
    h1[6] = (_Float16)fmaxf(fmaf(dr, a3.z, b3.z), 0.f);
    h1[7] = (_Float16)fmaxf(fmaf(dr, a3.w, b3.w), 0.f);
    *(half8_t*)(tl + r * 72 + cg * 16) = h0;
    *(half8_t*)(tl + r * 72 + cg * 16 + 8) = h1;
}

__global__ __launch_bounds__(256, 3)
void mfma_transform_kernel(const float* __restrict__ agg, const float* __restrict__ dinv,
                           const float* __restrict__ bprev, const float* __restrict__ W,
                           __half* __restrict__ gf_out) {
    __shared__ __align__(16) _Float16 tile[4][16 * 72];
    const int lane = threadIdx.x & 63, wid = threadIdx.x >> 6;
    const int tid4 = blockIdx.x * 4 + wid;
    if (tid4 >= NTILE) return;
    const int n0 = tid4 * 16;
    _Float16* tl = &tile[wid][0];

    hv_to_tile(agg, dinv, bprev, n0, lane, tl);

    const int kg = lane >> 4, n = lane & 15;
    half8_t B[4][2];
#pragma unroll
    for (int t = 0; t < 4; ++t)
#pragma unroll
        for (int h = 0; h < 2; ++h)
#pragma unroll
            for (int j = 0; j < 8; ++j)
                B[t][h][j] = (_Float16)W[(h * 32 + kg * 8 + j) * HID + t * 16 + n];

    __builtin_amdgcn_s_waitcnt(0);   // drain lgkm before cross-lane LDS read
    half8_t A0 = *(const half8_t*)(tl + n * 72 + kg * 8);
    half8_t A1 = *(const half8_t*)(tl + n * 72 + 32 + kg * 8);

    f32x4_t C[4];
#pragma unroll
    for (int t = 0; t < 4; ++t) {
        f32x4_t c = {0.f, 0.f, 0.f, 0.f};
        c = __builtin_amdgcn_mfma_f32_16x16x32_f16(A0, B[t][0], c, 0, 0, 0);
        c = __builtin_amdgcn_mfma_f32_16x16x32_f16(A1, B[t][1], c, 0, 0, 0);
        C[t] = c;
    }

    const int q = lane >> 4;
    float di4[4];
#pragma unroll
    for (int r = 0; r < 4; ++r) di4[r] = dinv[n0 + q * 4 + r];
#pragma unroll
    for (int t = 0; t < 4; ++t)
#pragma unroll
        for (int r = 0; r < 4; ++r)
            tl[(q * 4 + r) * 72 + t * 16 + n] = (_Float16)(C[t][r] * di4[r]);
    __builtin_amdgcn_s_waitcnt(0);
    const int r2 = lane >> 2, ch = lane & 3;
    uint4 v0 = *(const uint4*)(tl + r2 * 72 + ch * 16);
    uint4 v1 = *(const uint4*)(tl + r2 * 72 + ch * 16 + 8);
    *(uint4*)((__half*)gf_out + (size_t)(n0 + r2) * HID + ch * 16) = v0;
    *(uint4*)((__half*)gf_out + (size_t)(n0 + r2) * HID + ch * 16 + 8) = v1;
}

// ================= MFMA final: hv + MFMA (Wm1) + head + sigmoid =================

__global__ __launch_bounds__(256, 3)
void mfma_final_kernel(const float* __restrict__ agg, const float* __restrict__ dinv,
                       const float* __restrict__ b3, const float* __restrict__ Wm1,
                       const float* __restrict__ bm1, const float* __restrict__ Wm2,
                       const float* __restrict__ bm2, float* __restrict__ out) {
    __shared__ __align__(16) _Float16 tile[4][16 * 72];
    const int lane = threadIdx.x & 63, wid = threadIdx.x >> 6;
    const int tid4 = blockIdx.x * 4 + wid;
    if (tid4 >= NTILE) return;
    const int n0 = tid4 * 16;
    _Float16* tl = &tile[wid][0];

    hv_to_tile(agg, dinv, b3, n0, lane, tl);

    const int kg = lane >> 4, n = lane & 15;
    half8_t B[4][2];
#pragma unroll
    for (int t = 0; t < 4; ++t)
#pragma unroll
        for (int h = 0; h < 2; ++h)
#pragma unroll
            for (int j = 0; j < 8; ++j)
                B[t][h][j] = (_Float16)Wm1[(h * 32 + kg * 8 + j) * HID + t * 16 + n];

    __builtin_amdgcn_s_waitcnt(0);
    half8_t A0 = *(const half8_t*)(tl + n * 72 + kg * 8);
    half8_t A1 = *(const half8_t*)(tl + n * 72 + 32 + kg * 8);

    f32x4_t C[4];
#pragma unroll
    for (int t = 0; t < 4; ++t) {
        f32x4_t c = {0.f, 0.f, 0.f, 0.f};
        c = __builtin_amdgcn_mfma_f32_16x16x32_f16(A0, B[t][0], c, 0, 0, 0);
        c = __builtin_amdgcn_mfma_f32_16x16x32_f16(A1, B[t][1], c, 0, 0, 0);
        C[t] = c;
    }

    float bm14[4], wm24[4];
#pragma unroll
    for (int t = 0; t < 4; ++t) { bm14[t] = bm1[t * 16 + n]; wm24[t] = Wm2[t * 16 + n]; }
    const float bm20 = bm2[0];
    float part[4] = {0.f, 0.f, 0.f, 0.f};
#pragma unroll
    for (int t = 0; t < 4; ++t)
#pragma unroll
        for (int r = 0; r < 4; ++r)
            part[r] += fmaxf(C[t][r] + bm14[t], 0.0f) * wm24[t];
#pragma unroll
    for (int off = 1; off < 16; off <<= 1)
#pragma unroll
        for (int r = 0; r < 4; ++r) part[r] += __shfl_xor(part[r], off, 64);
    if (n == 0) {
        const int q = lane >> 4;
#pragma unroll
        for (int r = 0; r < 4; ++r)
            out[n0 + q * 4 + r] = 1.0f / (1.0f + expf(-(part[r] + bm20)));
    }
}

// ---------------- launch ----------------

extern "C" void kernel_launch(void* const* d_in, const int* in_sizes, int n_in,
                              void* d_out, int out_size, void* d_ws, size_t ws_size,
                              hipStream_t stream) {
    const float* x   = (const float*)d_in[0];
    const int*   ei  = (const int*)d_in[1];
    const float* W1  = (const float*)d_in[2];
    const float* b1  = (const float*)d_in[3];
    const float* W2  = (const float*)d_in[4];
    const float* b2  = (const float*)d_in[5];
    const float* W3  = (const float*)d_in[6];
    const float* b3  = (const float*)d_in[7];
    const float* Wm1 = (const float*)d_in[8];
    const float* bm1 = (const float*)d_in[9];
    const float* Wm2 = (const float*)d_in[10];
    const float* bm2 = (const float*)d_in[11];
    float* out = (float*)d_out;

    const int* src = ei;
    const int* dst = ei + N_EDGES;

    char* ws = (char*)d_ws;
    size_t off = 0;
    auto alloc = [&](size_t bytes) { size_t o = off; off = (off + bytes + 255) & ~(size_t)255; return (void*)(ws + o); };
    int*    rowptr = (int*)alloc(4ll * (N_NODES + 1));
    int*    histA  = (int*)alloc(4ll * NHIST);
    int*    baseL  = (int*)alloc(4ll * NHIST);
    int*    bsum   = (int*)alloc(4ll * NHB);
    int*    csr    = (int*)alloc(4ll * (EP + 64));       // +64 pad (zeros)
    float*  dinv   = (float*)alloc(4ll * N_NODES);
    __half* gfA    = (__half*)alloc(2ll * N_NODES * HID);
    __half* gfB    = (__half*)alloc(2ll * N_NODES * HID);
    float*  agg    = (float*)alloc(4ll * N_NODES * HID); // fp32 [N][64], 25.6 MB
    // preamble-only, alias agg: ebuf 6.4 MB + obuf 12.8 MB = 19.2 <= 25.6
    unsigned* ebuf = (unsigned*)agg;
    u64*      obuf = (u64*)((char*)agg + 4ll * N_EDGES);
    (void)ws_size;

    // --- CSR build v3: 5 dispatches, no memset, no global atomics ---
    hist_kernel<<<NCHUNK, 256, 0, stream>>>(dst, histA, csr);
    scang_block<<<NHB, 1024, 0, stream>>>(histA, baseL, bsum);
    scang_bsum<<<1, 256, 0, stream>>>(bsum);
    scatter_kernel<<<NCHUNK, 256, 0, stream>>>(src, dst, baseL, bsum, ebuf);
    rankfill_kernel<<<NBUCK, 256, 0, stream>>>(ebuf, baseL, bsum, obuf, rowptr, csr, dinv);

    // --- layers (split gather + MFMA transform) ---
    const int gblocks = N_NODES / (4 * NPN);   // 6250, exact
    const int fblocks = (NTILE + 3) / 4;       // 1563
    layer1_kernel<<<(N_NODES * HID + 255) / 256, 256, 0, stream>>>(x, W1, dinv, gfA);
    gather_kernel<<<gblocks, 256, 0, stream>>>(gfA, rowptr, csr, agg);
    mfma_transform_kernel<<<fblocks, 256, 0, stream>>>(agg, dinv, b1, W2, gfB);
    gather_kernel<<<gblocks, 256, 0, stream>>>(gfB, rowptr, csr, agg);
    mfma_transform_kernel<<<fblocks, 256, 0, stream>>>(agg, dinv, b2, W3, gfA);
    gather_kernel<<<gblocks, 256, 0, stream>>>(gfA, rowptr, csr, agg);
    mfma_final_kernel<<<fblocks, 256, 0, stream>>>(agg, dinv, b3, Wm1, bm1, Wm2, bm2, out);
}

// Round 14
// 255.220 us; speedup vs baseline: 1.2516x; 1.1304x over previous
//
#include <hip/hip_runtime.h>
#include <hip/hip_fp16.h>
#include <math.h>

#define N_NODES 100000
#define N_EDGES 1600000
#define EP (N_EDGES + N_NODES)   // edges incl self-loops
#define HID 64
#define NCHUNK 512                               // hist/scatter chunks
#define CE (N_EDGES / NCHUNK)                    // 3125 edges per chunk (exact)
#define NBUCK 391                                // buckets of 256 node-keys
#define NHIST (NBUCK * NCHUNK)                   // 200192
#define NHB ((NHIST + 1023) / 1024)              // 196 scan blocks
#define NTILE (N_NODES / 16)                     // 6250 MFMA tiles (exact)
#define STASH 8192                               // per-bucket stash (u32)
#define OBSTRIDE 4096                            // u64 overflow slots per bucket
#define NPN 4                                    // nodes per wave (gather), even

typedef _Float16 half8_t __attribute__((ext_vector_type(8)));
typedef _Float16 half4_t __attribute__((ext_vector_type(4)));
typedef float f32x4_t __attribute__((ext_vector_type(4)));
typedef unsigned long long u64;

// ================= bucketed CSR build v3 (5 dispatches, no memset) =================

__global__ __launch_bounds__(256)
void hist_kernel(const int* __restrict__ dst, int* __restrict__ histA,
                 int* __restrict__ csr) {
    __shared__ int hist[NBUCK];
    const int tid = threadIdx.x, c = blockIdx.x;
    for (int b = tid; b < NBUCK; b += 256) hist[b] = 0;
    __syncthreads();
    for (int e = c * CE + tid; e < (c + 1) * CE; e += 256)
        atomicAdd(&hist[dst[e] >> 8], 1);
    __syncthreads();
    for (int b = tid; b < NBUCK; b += 256) histA[b * NCHUNK + c] = hist[b];
    if (c == 0 && tid < 64) csr[EP + tid] = 0;   // zero pad for gather over-read
}

__global__ void scang_block(const int* __restrict__ in, int* __restrict__ baseL,
                            int* __restrict__ bsum) {
    __shared__ int wsum[16];
    int tid = threadIdx.x, lane = tid & 63, wid = tid >> 6;
    int i = blockIdx.x * 1024 + tid;
    int x = (i < NHIST) ? in[i] : 0;
    int inc = x;
#pragma unroll
    for (int off = 1; off < 64; off <<= 1) {
        int y = __shfl_up(inc, off, 64);
        if (lane >= off) inc += y;
    }
    if (lane == 63) wsum[wid] = inc;
    __syncthreads();
    if (tid == 0) {
        int s = 0;
#pragma unroll
        for (int j = 0; j < 16; ++j) { int t2 = wsum[j]; wsum[j] = s; s += t2; }
    }
    __syncthreads();
    if (i < NHIST) baseL[i] = wsum[wid] + inc - x;
    if (tid == 1023) bsum[blockIdx.x] = wsum[15] + inc;
}

__global__ void scang_bsum(int* __restrict__ bsum) {
    __shared__ int tmp[256];
    int t = threadIdx.x;
    tmp[t] = (t < NHB) ? bsum[t] : 0;
    __syncthreads();
    for (int off = 1; off < 256; off <<= 1) {
        int v = (t >= off) ? tmp[t - off] : 0;
        __syncthreads();
        tmp[t] += v;
        __syncthreads();
    }
    if (t < NHB) bsum[t] = (t == 0) ? 0 : tmp[t - 1];
}

__global__ __launch_bounds__(256)
void scatter_kernel(const int* __restrict__ src, const int* __restrict__ dst,
                    const int* __restrict__ baseL, const int* __restrict__ bsum,
                    unsigned* __restrict__ ebuf) {
    __shared__ int cur[NBUCK];
    const int tid = threadIdx.x, c = blockIdx.x;
    for (int b = tid; b < NBUCK; b += 256) {
        int idx = b * NCHUNK + c;
        cur[b] = baseL[idx] + bsum[idx >> 10];
    }
    __syncthreads();
    for (int e = c * CE + tid; e < (c + 1) * CE; e += 256) {
        int d = dst[e], s = src[e];
        int p = atomicAdd(&cur[d >> 8], 1);
        ebuf[p] = ((unsigned)(d & 255) << 17) | (unsigned)s;   // src < 2^17
    }
}

__global__ __launch_bounds__(256)
void rankfill_kernel(const unsigned* __restrict__ ebuf, const int* __restrict__ baseL,
                     const int* __restrict__ bsum, u64* __restrict__ obuf,
                     int* __restrict__ rowptr, int* __restrict__ csr,
                     float* __restrict__ dinv) {
    __shared__ int cnt[256];
    __shared__ int rpl[256];
    __shared__ int wsum[4];
    __shared__ int ocnt;
    __shared__ unsigned stash[STASH];
    const int tid = threadIdx.x, b = blockIdx.x;
    cnt[tid] = 0;
    if (tid == 0) ocnt = 0;
    __syncthreads();
    const int i0 = b * NCHUNK;
    const int R0 = baseL[i0] + bsum[i0 >> 10];
    const int i1 = (b + 1) * NCHUNK;
    const int R1 = (b == NBUCK - 1) ? N_EDGES : (baseL[i1] + bsum[i1 >> 10]);
    const int RL = R1 - R0;
    for (int off = tid; off < RL; off += 256) {
        unsigned v = ebuf[R0 + off];
        int key = (v >> 17) & 0xFF;
        int r = atomicAdd(&cnt[key], 1);
        if (off < STASH && r < 128) {
            stash[off] = ((unsigned)r << 25) | v;
        } else {
            if (off < STASH) stash[off] = 0xFFFFFFFFu;
            int oi = (off >= STASH) ? (off - STASH) : (2048 + atomicAdd(&ocnt, 1));
            obuf[(size_t)b * OBSTRIDE + oi] =
                ((u64)r << 40) | ((u64)key << 32) | (u64)(v & 0x1FFFFu);
        }
    }
    __syncthreads();
    const int lane = tid & 63, w = tid >> 6;
    int x = cnt[tid];
    int inc = x;
#pragma unroll
    for (int off = 1; off < 64; off <<= 1) {
        int y = __shfl_up(inc, off, 64);
        if (lane >= off) inc += y;
    }
    if (lane == 63) wsum[w] = inc;
    __syncthreads();
    int base = 0;
    for (int k = 0; k < 4; ++k) if (k < w) base += wsum[k];
    int pre = base + inc - x;
    const int n = b * 256 + tid;
    const int rpn = R0 + n + pre;
    rpl[tid] = rpn;
    if (n < N_NODES) {
        rowptr[n] = rpn;
        dinv[n] = rsqrtf((float)(x + 1));
        csr[rpn + x] = n;             // self-loop at end of node's list
    }
    if (b == NBUCK - 1 && tid == 0) rowptr[N_NODES] = EP;
    __syncthreads();
    const int lim = (RL < STASH) ? RL : STASH;
    for (int off = tid; off < lim; off += 256) {
        unsigned v = stash[off];
        if (v == 0xFFFFFFFFu) continue;
        csr[rpl[(v >> 17) & 0xFF] + (v >> 25)] = (int)(v & 0x1FFFFu);
    }
    for (int j = tid; j < RL - STASH; j += 256) {
        u64 pk = obuf[(size_t)b * OBSTRIDE + j];
        csr[rpl[(pk >> 32) & 0xFF] + (int)(pk >> 40)] = (int)(pk & 0x1FFFFu);
    }
    for (int j = tid; j < ocnt; j += 256) {
        u64 pk = obuf[(size_t)b * OBSTRIDE + 2048 + j];
        csr[rpl[(pk >> 32) & 0xFF] + (int)(pk >> 40)] = (int)(pk & 0x1FFFFu);
    }
}

// ---------------- layer 1: gf = fp16( dinv * (x @ W1) ), [N][64] ----------------

__global__ void layer1_kernel(const float* __restrict__ x, const float* __restrict__ W1,
                              const float* __restrict__ dinv, __half* __restrict__ gf) {
    int idx = blockIdx.x * blockDim.x + threadIdx.x;
    if (idx >= N_NODES * HID) return;
    int n = idx >> 6, c = idx & 63;
    float v = x[n * 3 + 0] * W1[c] + x[n * 3 + 1] * W1[HID + c]
            + x[n * 3 + 2] * W1[2 * HID + c];
    gf[idx] = __float2half(v * dinv[n]);
}

// ---------------- gather v3: 2-node interleaved pipeline + fused hv epilogue ----------------
// Pairs of nodes processed jointly: both nodes' index shfls + 8 feature loads
// issued before any accumulate (structural MLP). Epilogue computes
// hv = relu(di*agg + b) and stores fp16 directly (no fp32 agg round-trip).

__device__ __forceinline__ void addp(float4& a, uint2 u, bool pred) {
    __half2 h0 = *(__half2*)&u.x, h1 = *(__half2*)&u.y;
    float2 x = __half22float2(h0), y = __half22float2(h1);
    if (pred) { a.x += x.x; a.y += x.y; a.z += y.x; a.w += y.y; }
}

__device__ __forceinline__ void bfly_store(float4 acc, const float4 b4, float di,
                                           int g, int p, int n, __half* __restrict__ hv_out) {
    acc.x += __shfl_xor(acc.x, 16, 64);
    acc.y += __shfl_xor(acc.y, 16, 64);
    acc.z += __shfl_xor(acc.z, 16, 64);
    acc.w += __shfl_xor(acc.w, 16, 64);
    acc.x += __shfl_xor(acc.x, 32, 64);
    acc.y += __shfl_xor(acc.y, 32, 64);
    acc.z += __shfl_xor(acc.z, 32, 64);
    acc.w += __shfl_xor(acc.w, 32, 64);
    if (g == 0) {
        half4_t hv;
        hv[0] = (_Float16)fmaxf(fmaf(di, acc.x, b4.x), 0.f);
        hv[1] = (_Float16)fmaxf(fmaf(di, acc.y, b4.y), 0.f);
        hv[2] = (_Float16)fmaxf(fmaf(di, acc.z, b4.z), 0.f);
        hv[3] = (_Float16)fmaxf(fmaf(di, acc.w, b4.w), 0.f);
        *(half4_t*)(hv_out + (size_t)n * HID + p * 4) = hv;
    }
}

__global__ __launch_bounds__(256, 8)
void gather_kernel(const __half* __restrict__ gf, const int* __restrict__ rowptr,
                   const int* __restrict__ csr, const float* __restrict__ dinv,
                   const float* __restrict__ bias, __half* __restrict__ hv_out) {
    const int lane = threadIdx.x & 63, wid = threadIdx.x >> 6;
    const int g = lane >> 4, p = lane & 15;
    const int n0 = (blockIdx.x * 4 + wid) * NPN;
    int rp = rowptr[n0 + min(lane, NPN)];
    const uint2* gf2 = (const uint2*)gf;
    const float4 b4 = ((const float4*)bias)[p];
    int begv[NPN], cntv[NPN], idxv[NPN];
    int end_prev = __shfl(rp, 0, 64);
#pragma unroll
    for (int i = 0; i < NPN; ++i) {
        int end = __shfl(rp, i + 1, 64);
        begv[i] = end_prev;
        cntv[i] = end - end_prev;
        end_prev = end;
        idxv[i] = csr[begv[i] + lane];      // safe: csr padded by 64
    }
#pragma unroll
    for (int ii = 0; ii < NPN; ii += 2) {
        const int na = n0 + ii, nb = n0 + ii + 1;
        const int ca = cntv[ii], cb = cntv[ii + 1];
        const int ba = begv[ii], bb = begv[ii + 1];
        const int iva = idxv[ii], ivb = idxv[ii + 1];
        // issue both nodes' shfls + 8 feature loads up front
        int sa0 = __shfl(iva, g, 64),      sb0 = __shfl(ivb, g, 64);
        int sa1 = __shfl(iva, g + 4, 64),  sb1 = __shfl(ivb, g + 4, 64);
        int sa2 = __shfl(iva, g + 8, 64),  sb2 = __shfl(ivb, g + 8, 64);
        int sa3 = __shfl(iva, g + 12, 64), sb3 = __shfl(ivb, g + 12, 64);
        uint2 ua0 = gf2[(size_t)sa0 * 16 + p], ub0 = gf2[(size_t)sb0 * 16 + p];
        uint2 ua1 = gf2[(size_t)sa1 * 16 + p], ub1 = gf2[(size_t)sb1 * 16 + p];
        uint2 ua2 = gf2[(size_t)sa2 * 16 + p], ub2 = gf2[(size_t)sb2 * 16 + p];
        uint2 ua3 = gf2[(size_t)sa3 * 16 + p], ub3 = gf2[(size_t)sb3 * 16 + p];
        float4 accA = make_float4(0.f, 0.f, 0.f, 0.f);
        float4 accB = make_float4(0.f, 0.f, 0.f, 0.f);
        addp(accA, ua0, g + 0 < ca);  addp(accB, ub0, g + 0 < cb);
        addp(accA, ua1, g + 4 < ca);  addp(accB, ub1, g + 4 < cb);
        addp(accA, ua2, g + 8 < ca);  addp(accB, ub2, g + 8 < cb);
        addp(accA, ua3, g + 12 < ca); addp(accB, ub3, g + 12 < cb);
        if (ca > 16) {
#pragma unroll
            for (int k = 4; k < 8; ++k) {
                int e = g + 4 * k;
                int s = __shfl(iva, e, 64);
                addp(accA, gf2[(size_t)s * 16 + p], e < ca);
            }
            if (ca > 32) {
                for (int e = 32 + g; e < ca; e += 4) {
                    int s = (e < 64) ? __shfl(iva, e, 64) : csr[ba + e];
                    addp(accA, gf2[(size_t)s * 16 + p], true);
                }
            }
        }
        if (cb > 16) {
#pragma unroll
            for (int k = 4; k < 8; ++k) {
                int e = g + 4 * k;
                int s = __shfl(ivb, e, 64);
                addp(accB, gf2[(size_t)s * 16 + p], e < cb);
            }
            if (cb > 32) {
                for (int e = 32 + g; e < cb; e += 4) {
                    int s = (e < 64) ? __shfl(ivb, e, 64) : csr[bb + e];
                    addp(accB, gf2[(size_t)s * 16 + p], true);
                }
            }
        }
        bfly_store(accA, b4, dinv[na], g, p, na, hv_out);
        bfly_store(accB, b4, dinv[nb], g, p, nb, hv_out);
    }
}

// ================= MFMA transform: gf_out = fp16( di * (hv @ W) ) =================
// A-frags loaded directly from global hv (lane(m=lane&15,kg=lane>>4) reads 16B
// at hv[m][kg*8..+7] — coalesced within a 2KB tile). LDS only for epilogue.

__global__ __launch_bounds__(256, 3)
void mfma_transform_kernel(const __half* __restrict__ hv_in, const float* __restrict__ dinv,
                           const float* __restrict__ W, __half* __restrict__ gf_out) {
    __shared__ __align__(16) _Float16 tile[4][16 * 72];
    const int lane = threadIdx.x & 63, wid = threadIdx.x >> 6;
    const int tid4 = blockIdx.x * 4 + wid;
    if (tid4 >= NTILE) return;
    const int n0 = tid4 * 16;
    _Float16* tl = &tile[wid][0];
    const int kg = lane >> 4, n = lane & 15;

    half8_t A0 = *(const half8_t*)(hv_in + (size_t)(n0 + n) * HID + kg * 8);
    half8_t A1 = *(const half8_t*)(hv_in + (size_t)(n0 + n) * HID + 32 + kg * 8);

    half8_t B[4][2];
#pragma unroll
    for (int t = 0; t < 4; ++t)
#pragma unroll
        for (int h = 0; h < 2; ++h)
#pragma unroll
            for (int j = 0; j < 8; ++j)
                B[t][h][j] = (_Float16)W[(h * 32 + kg * 8 + j) * HID + t * 16 + n];

    f32x4_t C[4];
#pragma unroll
    for (int t = 0; t < 4; ++t) {
        f32x4_t c = {0.f, 0.f, 0.f, 0.f};
        c = __builtin_amdgcn_mfma_f32_16x16x32_f16(A0, B[t][0], c, 0, 0, 0);
        c = __builtin_amdgcn_mfma_f32_16x16x32_f16(A1, B[t][1], c, 0, 0, 0);
        C[t] = c;
    }

    const int q = lane >> 4;
    float di4[4];
#pragma unroll
    for (int r = 0; r < 4; ++r) di4[r] = dinv[n0 + q * 4 + r];
#pragma unroll
    for (int t = 0; t < 4; ++t)
#pragma unroll
        for (int r = 0; r < 4; ++r)
            tl[(q * 4 + r) * 72 + t * 16 + n] = (_Float16)(C[t][r] * di4[r]);
    __builtin_amdgcn_s_waitcnt(0);
    const int r2 = lane >> 2, ch = lane & 3;
    uint4 v0 = *(const uint4*)(tl + r2 * 72 + ch * 16);
    uint4 v1 = *(const uint4*)(tl + r2 * 72 + ch * 16 + 8);
    *(uint4*)((__half*)gf_out + (size_t)(n0 + r2) * HID + ch * 16) = v0;
    *(uint4*)((__half*)gf_out + (size_t)(n0 + r2) * HID + ch * 16 + 8) = v1;
}

// ================= MFMA final: hv @ Wm1 + head + sigmoid (no LDS) =================

__global__ __launch_bounds__(256, 3)
void mfma_final_kernel(const __half* __restrict__ hv_in, const float* __restrict__ Wm1,
                       const float* __restrict__ bm1, const float* __restrict__ Wm2,
                       const float* __restrict__ bm2, float* __restrict__ out) {
    const int lane = threadIdx.x & 63, wid = threadIdx.x >> 6;
    const int tid4 = blockIdx.x * 4 + wid;
    if (tid4 >= NTILE) return;
    const int n0 = tid4 * 16;
    const int kg = lane >> 4, n = lane & 15;

    half8_t A0 = *(const half8_t*)(hv_in + (size_t)(n0 + n) * HID + kg * 8);
    half8_t A1 = *(const half8_t*)(hv_in + (size_t)(n0 + n) * HID + 32 + kg * 8);

    half8_t B[4][2];
#pragma unroll
    for (int t = 0; t < 4; ++t)
#pragma unroll
        for (int h = 0; h < 2; ++h)
#pragma unroll
            for (int j = 0; j < 8; ++j)
                B[t][h][j] = (_Float16)Wm1[(h * 32 + kg * 8 + j) * HID + t * 16 + n];

    f32x4_t C[4];
#pragma unroll
    for (int t = 0; t < 4; ++t) {
        f32x4_t c = {0.f, 0.f, 0.f, 0.f};
        c = __builtin_amdgcn_mfma_f32_16x16x32_f16(A0, B[t][0], c, 0, 0, 0);
        c = __builtin_amdgcn_mfma_f32_16x16x32_f16(A1, B[t][1], c, 0, 0, 0);
        C[t] = c;
    }

    float bm14[4], wm24[4];
#pragma unroll
    for (int t = 0; t < 4; ++t) { bm14[t] = bm1[t * 16 + n]; wm24[t] = Wm2[t * 16 + n]; }
    const float bm20 = bm2[0];
    float part[4] = {0.f, 0.f, 0.f, 0.f};
#pragma unroll
    for (int t = 0; t < 4; ++t)
#pragma unroll
        for (int r = 0; r < 4; ++r)
            part[r] += fmaxf(C[t][r] + bm14[t], 0.0f) * wm24[t];
#pragma unroll
    for (int off = 1; off < 16; off <<= 1)
#pragma unroll
        for (int r = 0; r < 4; ++r) part[r] += __shfl_xor(part[r], off, 64);
    if (n == 0) {
        const int q = lane >> 4;
#pragma unroll
        for (int r = 0; r < 4; ++r)
            out[n0 + q * 4 + r] = 1.0f / (1.0f + expf(-(part[r] + bm20)));
    }
}

// ---------------- launch ----------------

extern "C" void kernel_launch(void* const* d_in, const int* in_sizes, int n_in,
                              void* d_out, int out_size, void* d_ws, size_t ws_size,
                              hipStream_t stream) {
    const float* x   = (const float*)d_in[0];
    const int*   ei  = (const int*)d_in[1];
    const float* W1  = (const float*)d_in[2];
    const float* b1  = (const float*)d_in[3];
    const float* W2  = (const float*)d_in[4];
    const float* b2  = (const float*)d_in[5];
    const float* W3  = (const float*)d_in[6];
    const float* b3  = (const float*)d_in[7];
    const float* Wm1 = (const float*)d_in[8];
    const float* bm1 = (const float*)d_in[9];
    const float* Wm2 = (const float*)d_in[10];
    const float* bm2 = (const float*)d_in[11];
    float* out = (float*)d_out;

    const int* src = ei;
    const int* dst = ei + N_EDGES;

    char* ws = (char*)d_ws;
    size_t off = 0;
    auto alloc = [&](size_t bytes) { size_t o = off; off = (off + bytes + 255) & ~(size_t)255; return (void*)(ws + o); };
    int*      rowptr = (int*)alloc(4ll * (N_NODES + 1));
    int*      histA  = (int*)alloc(4ll * NHIST);
    int*      baseL  = (int*)alloc(4ll * NHIST);
    int*      bsum   = (int*)alloc(4ll * NHB);
    int*      csr    = (int*)alloc(4ll * (EP + 64));       // +64 pad (zeros)
    float*    dinv   = (float*)alloc(4ll * N_NODES);
    __half*   gfA    = (__half*)alloc(2ll * N_NODES * HID);
    __half*   gfB    = (__half*)alloc(2ll * N_NODES * HID);
    __half*   hvbuf  = (__half*)alloc(2ll * N_NODES * HID);
    unsigned* ebuf   = (unsigned*)alloc(4ll * N_EDGES);
    u64*      obuf   = (u64*)alloc(8ll * (size_t)NBUCK * OBSTRIDE);
    (void)ws_size;

    // --- CSR build v3: 5 dispatches, no memset, no global atomics ---
    hist_kernel<<<NCHUNK, 256, 0, stream>>>(dst, histA, csr);
    scang_block<<<NHB, 1024, 0, stream>>>(histA, baseL, bsum);
    scang_bsum<<<1, 256, 0, stream>>>(bsum);
    scatter_kernel<<<NCHUNK, 256, 0, stream>>>(src, dst, baseL, bsum, ebuf);
    rankfill_kernel<<<NBUCK, 256, 0, stream>>>(ebuf, baseL, bsum, obuf, rowptr, csr, dinv);

    // --- layers: gather(+hv) then MFMA transform ---
    const int gblocks = N_NODES / (4 * NPN);   // 6250, exact
    const int fblocks = (NTILE + 3) / 4;       // 1563
    layer1_kernel<<<(N_NODES * HID + 255) / 256, 256, 0, stream>>>(x, W1, dinv, gfA);
    gather_kernel<<<gblocks, 256, 0, stream>>>(gfA, rowptr, csr, dinv, b1, hvbuf);
    mfma_transform_kernel<<<fblocks, 256, 0, stream>>>(hvbuf, dinv, W2, gfB);
    gather_kernel<<<gblocks, 256, 0, stream>>>(gfB, rowptr, csr, dinv, b2, hvbuf);
    mfma_transform_kernel<<<fblocks, 256, 0, stream>>>(hvbuf, dinv, W3, gfA);
    gather_kernel<<<gblocks, 256, 0, stream>>>(gfA, rowptr, csr, dinv, b3, hvbuf);
    mfma_final_kernel<<<fblocks, 256, 0, stream>>>(hvbuf, Wm1, bm1, Wm2, bm2, out);
}